// Round 5
// baseline (732.548 us; speedup 1.0000x reference)
//
#include <hip/hip_runtime.h>
#include <math.h>

#define B_    2048
#define LC    20
#define LQ    50
#define CTX   2048
#define CTXM  512
#define NEGV  -1e30f

typedef short bf16x8 __attribute__((ext_vector_type(8)));
typedef float f32x4  __attribute__((ext_vector_type(4)));
typedef unsigned int uint;
typedef unsigned short ushort;

// ---------------- helpers: fp32 -> bf16 hi/lo split ----------------
__device__ __forceinline__ void split4(float a0, float a1, float a2, float a3,
                                       uint2& hi, uint2& lo) {
    uint x0 = __float_as_uint(a0), x1 = __float_as_uint(a1),
         x2 = __float_as_uint(a2), x3 = __float_as_uint(a3);
    uint l0 = __float_as_uint(a0 - __uint_as_float(x0 & 0xffff0000u));
    uint l1 = __float_as_uint(a1 - __uint_as_float(x1 & 0xffff0000u));
    uint l2 = __float_as_uint(a2 - __uint_as_float(x2 & 0xffff0000u));
    uint l3 = __float_as_uint(a3 - __uint_as_float(x3 & 0xffff0000u));
    hi.x = __builtin_amdgcn_perm(x1, x0, 0x07060302u);
    hi.y = __builtin_amdgcn_perm(x3, x2, 0x07060302u);
    lo.x = __builtin_amdgcn_perm(l1, l0, 0x07060302u);
    lo.y = __builtin_amdgcn_perm(l3, l2, 0x07060302u);
}

__device__ __forceinline__ void split8(const float* x, bf16x8& h, bf16x8& l) {
    uint2 h0, l0, h1, l1;
    split4(x[0], x[1], x[2], x[3], h0, l0);
    split4(x[4], x[5], x[6], x[7], h1, l1);
    union { uint u[4]; bf16x8 v; } H, L;
    H.u[0] = h0.x; H.u[1] = h0.y; H.u[2] = h1.x; H.u[3] = h1.y;
    L.u[0] = l0.x; L.u[1] = l0.y; L.u[2] = l1.x; L.u[3] = l1.y;
    h = H.v; l = L.v;
}

// ---------------- Kernel 1: per-row scale = g[m] / ||trans_v[m,:]|| ----------------
__global__ __launch_bounds__(256)
void scale_kernel(const float* __restrict__ trans_v,
                  const float* __restrict__ trans_g,
                  float* __restrict__ scale) {
    int m = blockIdx.x;
    int t = threadIdx.x;
    const float* row = trans_v + (size_t)m * CTX;
    float ss = 0.f;
    for (int i = t; i < CTX; i += 256) { float v = row[i]; ss += v * v; }
    __shared__ float red[256];
    red[t] = ss;
    __syncthreads();
    for (int s = 128; s > 0; s >>= 1) {
        if (t < s) red[t] += red[t + s];
        __syncthreads();
    }
    if (t == 0) scale[m] = trans_g[m] / sqrtf(red[0]);
}

// ---------------- Kernel 1b: pre-split B = scale*trans_v into bf16 hi/lo ----------------
__global__ __launch_bounds__(256)
void bsplit_kernel(const float* __restrict__ Wt,
                   const float* __restrict__ scale,
                   ushort* __restrict__ Bh,
                   ushort* __restrict__ Bl) {
    int idx = blockIdx.x * 256 + threadIdx.x;   // 512*512 threads, 4 elems each
    int n  = idx >> 9;
    int c4 = (idx & 511) << 2;
    float s = scale[n];
    const float4 v = *(const float4*)&Wt[(size_t)n * CTX + c4];
    uint2 hi, lo;
    split4(v.x * s, v.y * s, v.z * s, v.w * s, hi, lo);
    *(uint2*)&Bh[(size_t)n * CTX + c4] = hi;
    *(uint2*)&Bl[(size_t)n * CTX + c4] = lo;
}

// ---------------- Kernel 2: bf16-split MFMA GEMM (B pre-split) ----------------
__global__ __launch_bounds__(256)
void gemm_kernel(const float* __restrict__ A,        // (40960, 2048) fp32
                 const ushort* __restrict__ Bh,      // (512, 2048) bf16 hi
                 const ushort* __restrict__ Bl,      // (512, 2048) bf16 lo
                 const float* __restrict__ trans_b,  // (512)
                 float* __restrict__ V)              // (40960, 512)
{
    // per row (128B): bytes [0,64) = hi (32 bf16), [64,128) = lo
    // swizzle: byte_in_row ^ ((row&7)<<4) on both write and read
    __shared__ char Ash[128 * 128] __attribute__((aligned(16)));
    __shared__ char Bsh[128 * 128] __attribute__((aligned(16)));

    int t = threadIdx.x;
    int orig = blockIdx.x;
    int wg = (orig & 7) * 160 + (orig >> 3);   // bijective XCD swizzle (1280 % 8 == 0)
    int n0 = (wg & 3) * 128;
    int m0 = (wg >> 2) * 128;

    int wid  = t >> 6;
    int lane = t & 63;
    int wm = (wid >> 1) << 6;
    int wn = (wid & 1) << 6;

    f32x4 acc[4][4];
#pragma unroll
    for (int i = 0; i < 4; i++)
#pragma unroll
        for (int j = 0; j < 4; j++) acc[i][j] = (f32x4){0.f, 0.f, 0.f, 0.f};

    int f4r[4], f4c[4], bsub[4];
    float4 ra[4];
    uint4  rb[4];
#pragma unroll
    for (int i = 0; i < 4; i++) {
        int c = t + i * 256;
        f4r[i]  = c >> 3;          // tile row 0..127
        f4c[i]  = (c & 7) << 2;    // fp32 col 0..28
        bsub[i] = c & 7;           // B 16B-chunk: 0..3 hi, 4..7 lo
        ra[i] = *(const float4*)&A[(size_t)(m0 + f4r[i]) * CTX + f4c[i]];
        const ushort* bsrc = (bsub[i] < 4 ? Bh : Bl) + (size_t)(n0 + f4r[i]) * CTX + (bsub[i] & 3) * 8;
        rb[i] = *(const uint4*)bsrc;
    }

    for (int it = 0; it < CTX / 32; ++it) {
        // ---- LDS write: A converted, B direct ----
#pragma unroll
        for (int i = 0; i < 4; i++) {
            int r  = f4r[i];
            int c8 = bsub[i] << 3;           // byte offset in hi half
            int sw = (r & 7) << 4;
            uint2 hi, lo;
            split4(ra[i].x, ra[i].y, ra[i].z, ra[i].w, hi, lo);
            *(uint2*)&Ash[r * 128 + (c8 ^ sw)]        = hi;
            *(uint2*)&Ash[r * 128 + ((64 + c8) ^ sw)] = lo;
            *(uint4*)&Bsh[r * 128 + ((bsub[i] * 16) ^ sw)] = rb[i];
        }
        __syncthreads();

        // ---- prefetch next tile (overlaps MFMA phase) ----
        if (it + 1 < CTX / 32) {
            int k0 = (it + 1) * 32;
#pragma unroll
            for (int i = 0; i < 4; i++) {
                ra[i] = *(const float4*)&A[(size_t)(m0 + f4r[i]) * CTX + k0 + f4c[i]];
                const ushort* bsrc = (bsub[i] < 4 ? Bh : Bl) + (size_t)(n0 + f4r[i]) * CTX + k0 + (bsub[i] & 3) * 8;
                rb[i] = *(const uint4*)bsrc;
            }
        }

        // ---- fragments + 48 MFMAs ----
        int q16 = (lane >> 4) << 4;
        bf16x8 ah[4], al[4], bx[4];
#pragma unroll
        for (int mt = 0; mt < 4; mt++) {
            int r  = wm + mt * 16 + (lane & 15);
            int sw = (r & 7) << 4;
            ah[mt] = *(const bf16x8*)&Ash[r * 128 + (q16 ^ sw)];
            al[mt] = *(const bf16x8*)&Ash[r * 128 + ((64 + q16) ^ sw)];
        }
#pragma unroll
        for (int nt = 0; nt < 4; nt++) {
            int r  = wn + nt * 16 + (lane & 15);
            int sw = (r & 7) << 4;
            bx[nt] = *(const bf16x8*)&Bsh[r * 128 + (q16 ^ sw)];   // Bh
        }
#pragma unroll
        for (int mt = 0; mt < 4; mt++)
#pragma unroll
            for (int nt = 0; nt < 4; nt++)
                acc[mt][nt] = __builtin_amdgcn_mfma_f32_16x16x32_bf16(ah[mt], bx[nt], acc[mt][nt], 0, 0, 0);
#pragma unroll
        for (int mt = 0; mt < 4; mt++)
#pragma unroll
            for (int nt = 0; nt < 4; nt++)
                acc[mt][nt] = __builtin_amdgcn_mfma_f32_16x16x32_bf16(al[mt], bx[nt], acc[mt][nt], 0, 0, 0);
#pragma unroll
        for (int nt = 0; nt < 4; nt++) {
            int r  = wn + nt * 16 + (lane & 15);
            int sw = (r & 7) << 4;
            bx[nt] = *(const bf16x8*)&Bsh[r * 128 + ((64 + q16) ^ sw)];  // Bl
        }
#pragma unroll
        for (int mt = 0; mt < 4; mt++)
#pragma unroll
            for (int nt = 0; nt < 4; nt++)
                acc[mt][nt] = __builtin_amdgcn_mfma_f32_16x16x32_bf16(ah[mt], bx[nt], acc[mt][nt], 0, 0, 0);
        __syncthreads();
    }

    // ---- epilogue: +trans_b, store ----
    int colbase = n0 + wn + (lane & 15);
    int rq4 = (lane >> 4) << 2;
#pragma unroll
    for (int nt = 0; nt < 4; nt++) {
        int col = colbase + nt * 16;
        float tb = trans_b[col];
#pragma unroll
        for (int mt = 0; mt < 4; mt++) {
            int m = m0 + wm + mt * 16 + rq4;
#pragma unroll
            for (int rg = 0; rg < 4; rg++)
                V[(size_t)(m + rg) * CTXM + col] = acc[mt][nt][rg] + tb;
        }
    }
}

// ---------------- Kernel 3: MFMA attention, no bulk LDS staging (unchanged) ----------------
__global__ __launch_bounds__(512, 4)
void attn_kernel(const float* __restrict__ Ques,    // (B, 512, 50)
                 const float* __restrict__ V_mask,  // (B, 20)
                 const float* __restrict__ Q_mask,  // (B, 50)
                 const float* __restrict__ w4V,     // (512)
                 const float* __restrict__ w4Q,     // (512)
                 const float* __restrict__ w4mlu,   // (512)
                 const float* __restrict__ bias,    // (1)
                 const float* __restrict__ V,       // (B*20, 512)
                 float* __restrict__ out)           // (B, 2048, 20)
{
    __shared__ float Ssh[LC][LQ];
    __shared__ float S1f[LC][LQ];
    __shared__ float S2f[LC][LQ];
    __shared__ unsigned short S1h[LC][72];
    __shared__ unsigned short S1l[LC][72];
    __shared__ unsigned short Bth[LC][40];
    __shared__ unsigned short Btl[LC][40];
    __shared__ float s1p[8][LQ];
    __shared__ float s0sh[LC];
    __shared__ float s1qsh[LQ];
    __shared__ float qmsh[LQ];
    __shared__ float vmsh[LC];

    int b = blockIdx.x;
    int t = threadIdx.x;
    int wid = t >> 6, lane = t & 63;
    int l15 = lane & 15;
    int kq  = (lane >> 4) << 3;
    int rq  = (lane >> 4) << 2;
    const float* Qb = Ques + (size_t)b * (CTXM * LQ);
    const float* Vb = V + (size_t)b * (LC * CTXM);

    if (t < LQ) qmsh[t] = Q_mask[(size_t)b * LQ + t];
    else if (t >= 64 && t < 64 + LC) vmsh[t - 64] = V_mask[(size_t)b * LC + (t - 64)];

    for (int l = wid; l < LC; l += 8) {
        float a = 0.f;
        const float* vr = Vb + (size_t)l * CTXM;
#pragma unroll
        for (int i = 0; i < CTXM / 64; i++)
            a = fmaf(vr[lane + 64 * i], w4V[lane + 64 * i], a);
#pragma unroll
        for (int o = 32; o > 0; o >>= 1) a += __shfl_xor(a, o);
        if (lane == 0) s0sh[l] = a;
    }

    {
        int q = (lane < LQ) ? lane : (LQ - 1);
        float a = 0.f;
        for (int i = 0; i < 64; i++) {
            int d = (wid << 6) + i;
            a = fmaf(Qb[(size_t)d * LQ + q], w4Q[d], a);
        }
        if (lane < LQ) s1p[wid][lane] = a;
    }

    int mt = wid >> 2, nt = wid & 3;
    f32x4 accS = {0.f, 0.f, 0.f, 0.f};
    {
        int lA = mt * 16 + l15; if (lA > LC - 1) lA = LC - 1;
        int qB = nt * 16 + l15; if (qB > LQ - 1) qB = LQ - 1;
        const float* vrow = Vb + (size_t)lA * CTXM;
        for (int kt = 0; kt < 16; kt++) {
            int d0 = kt * 32 + kq;
            float xa[8], xb[8];
            float4 va = *(const float4*)&vrow[d0];
            float4 vc = *(const float4*)&vrow[d0 + 4];
            float4 wa = *(const float4*)&w4mlu[d0];
            float4 wc = *(const float4*)&w4mlu[d0 + 4];
            xa[0] = va.x * wa.x; xa[1] = va.y * wa.y; xa[2] = va.z * wa.z; xa[3] = va.w * wa.w;
            xa[4] = vc.x * wc.x; xa[5] = vc.y * wc.y; xa[6] = vc.z * wc.z; xa[7] = vc.w * wc.w;
#pragma unroll
            for (int e = 0; e < 8; e++) xb[e] = Qb[(size_t)(d0 + e) * LQ + qB];
            bf16x8 vh, vl, qh, ql;
            split8(xa, vh, vl);
            split8(xb, qh, ql);
            accS = __builtin_amdgcn_mfma_f32_16x16x32_bf16(vh, qh, accS, 0, 0, 0);
            accS = __builtin_amdgcn_mfma_f32_16x16x32_bf16(vl, qh, accS, 0, 0, 0);
            accS = __builtin_amdgcn_mfma_f32_16x16x32_bf16(vh, ql, accS, 0, 0, 0);
        }
    }
    __syncthreads();

    if (t < LQ) {
        float s = 0.f;
#pragma unroll
        for (int w = 0; w < 8; w++) s += s1p[w][t];
        s1qsh[t] = s;
    }
    __syncthreads();

    {
        float bb = bias[0];
        int q = nt * 16 + l15;
#pragma unroll
        for (int r = 0; r < 4; r++) {
            int l = mt * 16 + rq + r;
            if (l < LC && q < LQ)
                Ssh[l][q] = accS[r] + s0sh[l] + s1qsh[q] + bb;
        }
    }
    __syncthreads();

    for (int l = wid; l < LC; l += 8) {
        float x;
        if (lane < LQ) {
            float qm = qmsh[lane];
            x = Ssh[l][lane] * qm + (1.f - qm) * NEGV;
        } else x = -INFINITY;
        float mx = x;
#pragma unroll
        for (int o = 32; o > 0; o >>= 1) mx = fmaxf(mx, __shfl_xor(mx, o));
        float e = (lane < LQ) ? expf(x - mx) : 0.f;
        float sum = e;
#pragma unroll
        for (int o = 32; o > 0; o >>= 1) sum += __shfl_xor(sum, o);
        float p = e / sum;
        if (lane < LQ) S1f[l][lane] = p;
        uint xu = __float_as_uint(p);
        float rl = p - __uint_as_float(xu & 0xffff0000u);
        unsigned short hs = (unsigned short)(xu >> 16);
        unsigned short ls = (unsigned short)(__float_as_uint(rl) >> 16);
        S1h[l][lane] = (lane < LQ) ? hs : (unsigned short)0;
        S1l[l][lane] = (lane < LQ) ? ls : (unsigned short)0;
    }

    for (int ci = 0; ci < 7; ci++) {
        int c = wid * 7 + ci;
        if (c < LQ) {
            float x;
            if (lane < LC) {
                float vm = vmsh[lane];
                x = Ssh[lane][c] * vm + (1.f - vm) * NEGV;
            } else x = -INFINITY;
            float mx = x;
#pragma unroll
            for (int o = 32; o > 0; o >>= 1) mx = fmaxf(mx, __shfl_xor(mx, o));
            float e = (lane < LC) ? expf(x - mx) : 0.f;
            float sum = e;
#pragma unroll
            for (int o = 32; o > 0; o >>= 1) sum += __shfl_xor(sum, o);
            if (lane < LC) S2f[lane][c] = e / sum;
        }
    }
    __syncthreads();

    if (t < LC * LC) {
        int l = t % LC, m = t / LC;
        float s = 0.f;
#pragma unroll
        for (int j = 0; j < LQ; j++) s = fmaf(S1f[l][j], S2f[m][j], s);
        uint xu = __float_as_uint(s);
        float rl = s - __uint_as_float(xu & 0xffff0000u);
        Bth[l][m] = (unsigned short)(xu >> 16);
        Btl[l][m] = (unsigned short)(__float_as_uint(rl) >> 16);
    }
    if (t < 240) {
        int l = t % LC, m = LC + t / LC;
        Bth[l][m] = 0; Btl[l][m] = 0;
    }
    __syncthreads();

    float* outb = out + (size_t)b * (4 * CTXM * LC);
#pragma unroll 1
    for (int i = 0; i < 4; i++) {
        int dt = wid + 8 * i;
        int d0 = dt * 16;
        int dq = d0 + l15;
        const float* qrow = Qb + (size_t)dq * LQ;
        float xa[8];
        bf16x8 qh0, ql0, qh1, ql1;
#pragma unroll
        for (int e = 0; e < 8; e++) xa[e] = qrow[kq + e];
        split8(xa, qh0, ql0);
#pragma unroll
        for (int e = 0; e < 8; e++) {
            int j = 32 + kq + e;
            xa[e] = (j < LQ) ? qrow[j] : 0.f;
        }
        split8(xa, qh1, ql1);
        float xv[8];
#pragma unroll
        for (int e = 0; e < 8; e++) {
            int m = kq + e;
            int mc = (m < LC) ? m : 0;
            float vv = Vb[(size_t)mc * CTXM + d0 + l15];
            xv[e] = (m < LC) ? vv : 0.f;
        }
        bf16x8 vth, vtl;
        split8(xv, vth, vtl);

        f32x4 accA[2] = {{0.f,0.f,0.f,0.f},{0.f,0.f,0.f,0.f}};
        f32x4 accB[2] = {{0.f,0.f,0.f,0.f},{0.f,0.f,0.f,0.f}};
#pragma unroll
        for (int n2 = 0; n2 < 2; n2++) {
            int lS = n2 * 16 + l15; if (lS > LC - 1) lS = LC - 1;
            bf16x8 s1h0 = *(const bf16x8*)&S1h[lS][kq];
            bf16x8 s1l0 = *(const bf16x8*)&S1l[lS][kq];
            bf16x8 s1h1 = *(const bf16x8*)&S1h[lS][32 + kq];
            bf16x8 s1l1 = *(const bf16x8*)&S1l[lS][32 + kq];
            accA[n2] = __builtin_amdgcn_mfma_f32_16x16x32_bf16(qh0, s1h0, accA[n2], 0, 0, 0);
            accA[n2] = __builtin_amdgcn_mfma_f32_16x16x32_bf16(ql0, s1h0, accA[n2], 0, 0, 0);
            accA[n2] = __builtin_amdgcn_mfma_f32_16x16x32_bf16(qh0, s1l0, accA[n2], 0, 0, 0);
            accA[n2] = __builtin_amdgcn_mfma_f32_16x16x32_bf16(qh1, s1h1, accA[n2], 0, 0, 0);
            accA[n2] = __builtin_amdgcn_mfma_f32_16x16x32_bf16(ql1, s1h1, accA[n2], 0, 0, 0);
            accA[n2] = __builtin_amdgcn_mfma_f32_16x16x32_bf16(qh1, s1l1, accA[n2], 0, 0, 0);
            bf16x8 bh = *(const bf16x8*)&Bth[lS][kq];
            bf16x8 bl = *(const bf16x8*)&Btl[lS][kq];
            accB[n2] = __builtin_amdgcn_mfma_f32_16x16x32_bf16(vth, bh, accB[n2], 0, 0, 0);
            accB[n2] = __builtin_amdgcn_mfma_f32_16x16x32_bf16(vtl, bh, accB[n2], 0, 0, 0);
            accB[n2] = __builtin_amdgcn_mfma_f32_16x16x32_bf16(vth, bl, accB[n2], 0, 0, 0);
        }

#pragma unroll
        for (int n2 = 0; n2 < 2; n2++) {
            int l = n2 * 16 + l15;
            if (l < LC) {
#pragma unroll
                for (int r = 0; r < 4; r++) {
                    int d = d0 + rq + r;
                    float vv = Vb[(size_t)l * CTXM + d];
                    float a  = accA[n2][r];
                    float bv = accB[n2][r];
                    size_t base = (size_t)d * LC + l;
                    outb[base]                 = vv;
                    outb[base + CTXM * LC]     = a;
                    outb[base + 2 * CTXM * LC] = vv * a;
                    outb[base + 3 * CTXM * LC] = vv * bv;
                }
            }
        }
    }
}

extern "C" void kernel_launch(void* const* d_in, const int* in_sizes, int n_in,
                              void* d_out, int out_size, void* d_ws, size_t ws_size,
                              hipStream_t stream) {
    const float* Vid   = (const float*)d_in[0];
    const float* Ques  = (const float*)d_in[1];
    const float* Vmask = (const float*)d_in[2];
    const float* Qmask = (const float*)d_in[3];
    const float* tv    = (const float*)d_in[4];
    const float* tg    = (const float*)d_in[5];
    const float* tb    = (const float*)d_in[6];
    const float* w4V   = (const float*)d_in[7];
    const float* w4Q   = (const float*)d_in[8];
    const float* w4mlu = (const float*)d_in[9];
    const float* bias  = (const float*)d_in[10];
    float* out = (float*)d_out;

    float*  scale = (float*)d_ws;                    // 512 f
    float*  V     = scale + 512;                     // 40960*512 f (84 MB)
    ushort* Bh    = (ushort*)(V + (size_t)40960 * 512);  // 512*2048 bf16 (2 MB)
    ushort* Bl    = Bh + (size_t)512 * 2048;             // 512*2048 bf16 (2 MB)

    scale_kernel<<<512, 256, 0, stream>>>(tv, tg, scale);
    bsplit_kernel<<<1024, 256, 0, stream>>>(tv, scale, Bh, Bl);
    gemm_kernel<<<1280, 256, 0, stream>>>(Vid, Bh, Bl, tb, V);
    attn_kernel<<<B_, 512, 0, stream>>>(Ques, Vmask, Qmask, w4V, w4Q, w4mlu, bias, V, out);
}

// Round 7
// 583.095 us; speedup vs baseline: 1.2563x; 1.2563x over previous
//
#include <hip/hip_runtime.h>
#include <math.h>

#define B_    2048
#define LC    20
#define LQ    50
#define CTX   2048
#define CTXM  512
#define NEGV  -1e30f

typedef __fp16 half8 __attribute__((ext_vector_type(8)));
typedef __fp16 f16x2 __attribute__((ext_vector_type(2)));
typedef float f32x4  __attribute__((ext_vector_type(4)));
typedef unsigned int uint;

// ---------------- helpers: fp32 -> fp16 conversions ----------------
// 4 f32 -> 4 f16 (RTZ), packed in uint2
__device__ __forceinline__ uint2 cvt4_pack(float4 v) {
    union { f16x2 h[2]; uint2 u; } r;
    r.h[0] = __builtin_amdgcn_cvt_pkrtz(v.x, v.y);
    r.h[1] = __builtin_amdgcn_cvt_pkrtz(v.z, v.w);
    return r.u;
}
// fp16 2-term split: x = hi + lo, |err| ~ 2^-21 |x|
__device__ __forceinline__ void split4_f16(float4 v, uint2& hi, uint2& lo) {
    f16x2 h0 = __builtin_amdgcn_cvt_pkrtz(v.x, v.y);
    f16x2 h1 = __builtin_amdgcn_cvt_pkrtz(v.z, v.w);
    float r0 = v.x - (float)h0[0];
    float r1 = v.y - (float)h0[1];
    float r2 = v.z - (float)h1[0];
    float r3 = v.w - (float)h1[1];
    f16x2 l0 = __builtin_amdgcn_cvt_pkrtz(r0, r1);
    f16x2 l1 = __builtin_amdgcn_cvt_pkrtz(r2, r3);
    union { f16x2 h[2]; uint2 u; } H, L;
    H.h[0] = h0; H.h[1] = h1; L.h[0] = l0; L.h[1] = l1;
    hi = H.u; lo = L.u;
}
// 8 f32 -> half8 (single term)
__device__ __forceinline__ half8 cvt8(const float* x) {
    union { f16x2 h[4]; half8 v; } r;
    r.h[0] = __builtin_amdgcn_cvt_pkrtz(x[0], x[1]);
    r.h[1] = __builtin_amdgcn_cvt_pkrtz(x[2], x[3]);
    r.h[2] = __builtin_amdgcn_cvt_pkrtz(x[4], x[5]);
    r.h[3] = __builtin_amdgcn_cvt_pkrtz(x[6], x[7]);
    return r.v;
}

// ---------------- Kernel 1: per-row scale = g[m] / ||trans_v[m,:]|| ----------------
__global__ __launch_bounds__(256)
void scale_kernel(const float* __restrict__ trans_v,
                  const float* __restrict__ trans_g,
                  float* __restrict__ scale) {
    int m = blockIdx.x;
    int t = threadIdx.x;
    const float* row = trans_v + (size_t)m * CTX;
    float ss = 0.f;
    for (int i = t; i < CTX; i += 256) { float v = row[i]; ss += v * v; }
    __shared__ float red[256];
    red[t] = ss;
    __syncthreads();
    for (int s = 128; s > 0; s >>= 1) {
        if (t < s) red[t] += red[t + s];
        __syncthreads();
    }
    if (t == 0) scale[m] = trans_g[m] / sqrtf(red[0]);
}

// ---------------- Kernel 2: fp16 2-term MFMA GEMM (R4 structure) ----------------
// V = A @ (scale*Wt)^T + trans_b;  A fp16 single-term, B fp16 hi/lo split.
__global__ __launch_bounds__(256)
void gemm_kernel(const float* __restrict__ A,        // (40960, 2048) fp32
                 const float* __restrict__ Wt,       // (512, 2048) fp32
                 const float* __restrict__ scale,    // (512)
                 const float* __restrict__ trans_b,  // (512)
                 float* __restrict__ V)              // (40960, 512)
{
    // A rows 128B: fp16 k0..31 at bytes 0-63 (upper half unused)
    // B rows 128B: hi fp16 bytes 0-63, lo fp16 bytes 64-127
    // swizzle: byte_in_row ^ ((row&7)<<4) on both write and read (proven R2-R4)
    __shared__ char Ash[128 * 128] __attribute__((aligned(16)));
    __shared__ char Bsh[128 * 128] __attribute__((aligned(16)));
    __shared__ float sc[128];

    int t = threadIdx.x;
    int orig = blockIdx.x;
    int wg = (orig & 7) * 160 + (orig >> 3);   // bijective XCD swizzle (1280 % 8 == 0)
    int n0 = (wg & 3) * 128;
    int m0 = (wg >> 2) * 128;

    if (t < 128) sc[t] = scale[n0 + t];

    int wid  = t >> 6;
    int lane = t & 63;
    int wm = (wid >> 1) << 6;
    int wn = (wid & 1) << 6;

    f32x4 acc[4][4];
#pragma unroll
    for (int i = 0; i < 4; i++)
#pragma unroll
        for (int j = 0; j < 4; j++) acc[i][j] = (f32x4){0.f, 0.f, 0.f, 0.f};

    int f4r[4], f4c[4];
    float4 ra[4], rb[4];
#pragma unroll
    for (int i = 0; i < 4; i++) {
        int c = t + i * 256;
        f4r[i] = c >> 3;           // tile row 0..127
        f4c[i] = (c & 7) << 2;     // fp32 col 0..28
        ra[i] = *(const float4*)&A [(size_t)(m0 + f4r[i]) * CTX + f4c[i]];
        rb[i] = *(const float4*)&Wt[(size_t)(n0 + f4r[i]) * CTX + f4c[i]];
    }
    __syncthreads();   // sc ready

    for (int it = 0; it < CTX / 32; ++it) {
        // ---- convert + LDS write ----
#pragma unroll
        for (int i = 0; i < 4; i++) {
            int r  = f4r[i];
            int c8 = (f4c[i] >> 2) << 3;     // byte offset (2B/elem * 4 elems)
            int sw = (r & 7) << 4;
            *(uint2*)&Ash[r * 128 + (c8 ^ sw)] = cvt4_pack(ra[i]);
            float s = sc[r];
            float4 bs = rb[i];
            bs.x *= s; bs.y *= s; bs.z *= s; bs.w *= s;
            uint2 hi, lo;
            split4_f16(bs, hi, lo);
            *(uint2*)&Bsh[r * 128 + (c8 ^ sw)]        = hi;
            *(uint2*)&Bsh[r * 128 + ((64 + c8) ^ sw)] = lo;
        }
        __syncthreads();

        // ---- prefetch next tile (overlaps MFMA phase) ----
        if (it + 1 < CTX / 32) {
            int k0 = (it + 1) * 32;
#pragma unroll
            for (int i = 0; i < 4; i++) {
                ra[i] = *(const float4*)&A [(size_t)(m0 + f4r[i]) * CTX + k0 + f4c[i]];
                rb[i] = *(const float4*)&Wt[(size_t)(n0 + f4r[i]) * CTX + k0 + f4c[i]];
            }
        }

        // ---- fragments + 32 MFMAs ----
        int q16 = (lane >> 4) << 4;
        half8 af[4], bx[4];
#pragma unroll
        for (int mt = 0; mt < 4; mt++) {
            int r  = wm + mt * 16 + (lane & 15);
            int sw = (r & 7) << 4;
            af[mt] = *(const half8*)&Ash[r * 128 + (q16 ^ sw)];
        }
#pragma unroll
        for (int nt = 0; nt < 4; nt++) {
            int r  = wn + nt * 16 + (lane & 15);
            int sw = (r & 7) << 4;
            bx[nt] = *(const half8*)&Bsh[r * 128 + (q16 ^ sw)];   // Bh
        }
#pragma unroll
        for (int mt = 0; mt < 4; mt++)
#pragma unroll
            for (int nt = 0; nt < 4; nt++)
                acc[mt][nt] = __builtin_amdgcn_mfma_f32_16x16x32_f16(af[mt], bx[nt], acc[mt][nt], 0, 0, 0);
#pragma unroll
        for (int nt = 0; nt < 4; nt++) {
            int r  = wn + nt * 16 + (lane & 15);
            int sw = (r & 7) << 4;
            bx[nt] = *(const half8*)&Bsh[r * 128 + ((64 + q16) ^ sw)];  // Bl
        }
#pragma unroll
        for (int mt = 0; mt < 4; mt++)
#pragma unroll
            for (int nt = 0; nt < 4; nt++)
                acc[mt][nt] = __builtin_amdgcn_mfma_f32_16x16x32_f16(af[mt], bx[nt], acc[mt][nt], 0, 0, 0);
        __syncthreads();
    }

    // ---- epilogue: +trans_b, store ----
    int colbase = n0 + wn + (lane & 15);
    int rq4 = (lane >> 4) << 2;
#pragma unroll
    for (int nt = 0; nt < 4; nt++) {
        int col = colbase + nt * 16;
        float tb = trans_b[col];
#pragma unroll
        for (int mt = 0; mt < 4; mt++) {
            int m = m0 + wm + mt * 16 + rq4;
#pragma unroll
            for (int rg = 0; rg < 4; rg++)
                V[(size_t)(m + rg) * CTXM + col] = acc[mt][nt][rg] + tb;
        }
    }
}

// ---------------- Kernel 3: MFMA attention (fp16 operands) ----------------
__global__ __launch_bounds__(512, 4)
void attn_kernel(const float* __restrict__ Ques,    // (B, 512, 50)
                 const float* __restrict__ V_mask,  // (B, 20)
                 const float* __restrict__ Q_mask,  // (B, 50)
                 const float* __restrict__ w4V,     // (512)
                 const float* __restrict__ w4Q,     // (512)
                 const float* __restrict__ w4mlu,   // (512)
                 const float* __restrict__ bias,    // (1)
                 const float* __restrict__ V,       // (B*20, 512)
                 float* __restrict__ out)           // (B, 2048, 20)
{
    __shared__ float Ssh[LC][LQ];
    __shared__ float S1f[LC][LQ];
    __shared__ float S2f[LC][LQ];
    __shared__ __fp16 S1h[LC][72];   // fp16 hi, cols 50..63 zeroed
    __shared__ __fp16 S1l[LC][72];   // fp16 lo
    __shared__ __fp16 Bth[LC][40];   // fp16 hi, cols 20..31 zeroed
    __shared__ __fp16 Btl[LC][40];
    __shared__ float s1p[8][LQ];
    __shared__ float s0sh[LC];
    __shared__ float s1qsh[LQ];
    __shared__ float qmsh[LQ];
    __shared__ float vmsh[LC];

    int b = blockIdx.x;
    int t = threadIdx.x;
    int wid = t >> 6, lane = t & 63;
    int l15 = lane & 15;
    int kq  = (lane >> 4) << 3;
    int rq  = (lane >> 4) << 2;
    const float* Qb = Ques + (size_t)b * (CTXM * LQ);
    const float* Vb = V + (size_t)b * (LC * CTXM);

    if (t < LQ) qmsh[t] = Q_mask[(size_t)b * LQ + t];
    else if (t >= 64 && t < 64 + LC) vmsh[t - 64] = V_mask[(size_t)b * LC + (t - 64)];

    for (int l = wid; l < LC; l += 8) {
        float a = 0.f;
        const float* vr = Vb + (size_t)l * CTXM;
#pragma unroll
        for (int i = 0; i < CTXM / 64; i++)
            a = fmaf(vr[lane + 64 * i], w4V[lane + 64 * i], a);
#pragma unroll
        for (int o = 32; o > 0; o >>= 1) a += __shfl_xor(a, o);
        if (lane == 0) s0sh[l] = a;
    }

    {
        int q = (lane < LQ) ? lane : (LQ - 1);
        float a = 0.f;
        for (int i = 0; i < 64; i++) {
            int d = (wid << 6) + i;
            a = fmaf(Qb[(size_t)d * LQ + q], w4Q[d], a);
        }
        if (lane < LQ) s1p[wid][lane] = a;
    }

    // ---- s2 via fp16 MFMA (single term each side) ----
    int mt = wid >> 2, nt = wid & 3;
    f32x4 accS = {0.f, 0.f, 0.f, 0.f};
    {
        int lA = mt * 16 + l15; if (lA > LC - 1) lA = LC - 1;
        int qB = nt * 16 + l15; if (qB > LQ - 1) qB = LQ - 1;
        const float* vrow = Vb + (size_t)lA * CTXM;
        for (int kt = 0; kt < 16; kt++) {
            int d0 = kt * 32 + kq;
            float xa[8], xb[8];
            float4 va = *(const float4*)&vrow[d0];
            float4 vc = *(const float4*)&vrow[d0 + 4];
            float4 wa = *(const float4*)&w4mlu[d0];
            float4 wc = *(const float4*)&w4mlu[d0 + 4];
            xa[0] = va.x * wa.x; xa[1] = va.y * wa.y; xa[2] = va.z * wa.z; xa[3] = va.w * wa.w;
            xa[4] = vc.x * wc.x; xa[5] = vc.y * wc.y; xa[6] = vc.z * wc.z; xa[7] = vc.w * wc.w;
#pragma unroll
            for (int e = 0; e < 8; e++) xb[e] = Qb[(size_t)(d0 + e) * LQ + qB];
            half8 vf = cvt8(xa);
            half8 qf = cvt8(xb);
            accS = __builtin_amdgcn_mfma_f32_16x16x32_f16(vf, qf, accS, 0, 0, 0);
        }
    }
    __syncthreads();   // BAR1

    if (t < LQ) {
        float s = 0.f;
#pragma unroll
        for (int w = 0; w < 8; w++) s += s1p[w][t];
        s1qsh[t] = s;
    }
    __syncthreads();   // BAR2

    {
        float bb = bias[0];
        int q = nt * 16 + l15;
#pragma unroll
        for (int r = 0; r < 4; r++) {
            int l = mt * 16 + rq + r;
            if (l < LC && q < LQ)
                Ssh[l][q] = accS[r] + s0sh[l] + s1qsh[q] + bb;
        }
    }
    __syncthreads();   // BAR3

    for (int l = wid; l < LC; l += 8) {
        float x;
        if (lane < LQ) {
            float qm = qmsh[lane];
            x = Ssh[l][lane] * qm + (1.f - qm) * NEGV;
        } else x = -INFINITY;
        float mx = x;
#pragma unroll
        for (int o = 32; o > 0; o >>= 1) mx = fmaxf(mx, __shfl_xor(mx, o));
        float e = (lane < LQ) ? expf(x - mx) : 0.f;
        float sum = e;
#pragma unroll
        for (int o = 32; o > 0; o >>= 1) sum += __shfl_xor(sum, o);
        float p = e / sum;
        if (lane < LQ) S1f[l][lane] = p;
        __fp16 hs = (__fp16)p;
        __fp16 ls = (__fp16)(p - (float)hs);
        S1h[l][lane] = (lane < LQ) ? hs : (__fp16)0;
        S1l[l][lane] = (lane < LQ) ? ls : (__fp16)0;
    }

    for (int ci = 0; ci < 7; ci++) {
        int c = wid * 7 + ci;
        if (c < LQ) {
            float x;
            if (lane < LC) {
                float vm = vmsh[lane];
                x = Ssh[lane][c] * vm + (1.f - vm) * NEGV;
            } else x = -INFINITY;
            float mx = x;
#pragma unroll
            for (int o = 32; o > 0; o >>= 1) mx = fmaxf(mx, __shfl_xor(mx, o));
            float e = (lane < LC) ? expf(x - mx) : 0.f;
            float sum = e;
#pragma unroll
            for (int o = 32; o > 0; o >>= 1) sum += __shfl_xor(sum, o);
            if (lane < LC) S2f[lane][c] = e / sum;
        }
    }
    __syncthreads();   // BAR4

    if (t < LC * LC) {
        int l = t % LC, m = t / LC;
        float s = 0.f;
#pragma unroll
        for (int j = 0; j < LQ; j++) s = fmaf(S1f[l][j], S2f[m][j], s);
        __fp16 hs = (__fp16)s;
        Bth[l][m] = hs;
        Btl[l][m] = (__fp16)(s - (float)hs);
    }
    if (t < 240) {
        int l = t % LC, m = LC + t / LC;
        Bth[l][m] = (__fp16)0; Btl[l][m] = (__fp16)0;
    }
    __syncthreads();   // BAR5

    // ---- Phase B: A^T and Bv^T via fp16 MFMA + fused epilogue ----
    float* outb = out + (size_t)b * (4 * CTXM * LC);
#pragma unroll 1
    for (int i = 0; i < 4; i++) {
        int dt = wid + 8 * i;
        int d0 = dt * 16;
        int dq = d0 + l15;
        const float* qrow = Qb + (size_t)dq * LQ;
        float xa[8];
#pragma unroll
        for (int e = 0; e < 8; e++) xa[e] = qrow[kq + e];          // j <= 31 < 50
        half8 qf0 = cvt8(xa);
#pragma unroll
        for (int e = 0; e < 8; e++) {
            int j = 32 + kq + e;
            xa[e] = (j < LQ) ? qrow[j] : 0.f;
        }
        half8 qf1 = cvt8(xa);
        float xv[8];
#pragma unroll
        for (int e = 0; e < 8; e++) {
            int m = kq + e;
            int mc = (m < LC) ? m : 0;
            float vv = Vb[(size_t)mc * CTXM + d0 + l15];
            xv[e] = (m < LC) ? vv : 0.f;
        }
        half8 vt = cvt8(xv);

        f32x4 accA[2] = {{0.f,0.f,0.f,0.f},{0.f,0.f,0.f,0.f}};
        f32x4 accB[2] = {{0.f,0.f,0.f,0.f},{0.f,0.f,0.f,0.f}};
#pragma unroll
        for (int n2 = 0; n2 < 2; n2++) {
            int lS = n2 * 16 + l15; if (lS > LC - 1) lS = LC - 1;
            half8 s1h0 = *(const half8*)&S1h[lS][kq];
            half8 s1l0 = *(const half8*)&S1l[lS][kq];
            half8 s1h1 = *(const half8*)&S1h[lS][32 + kq];
            half8 s1l1 = *(const half8*)&S1l[lS][32 + kq];
            accA[n2] = __builtin_amdgcn_mfma_f32_16x16x32_f16(qf0, s1h0, accA[n2], 0, 0, 0);
            accA[n2] = __builtin_amdgcn_mfma_f32_16x16x32_f16(qf0, s1l0, accA[n2], 0, 0, 0);
            accA[n2] = __builtin_amdgcn_mfma_f32_16x16x32_f16(qf1, s1h1, accA[n2], 0, 0, 0);
            accA[n2] = __builtin_amdgcn_mfma_f32_16x16x32_f16(qf1, s1l1, accA[n2], 0, 0, 0);
            half8 bh = *(const half8*)&Bth[lS][kq];
            half8 bl = *(const half8*)&Btl[lS][kq];
            accB[n2] = __builtin_amdgcn_mfma_f32_16x16x32_f16(vt, bh, accB[n2], 0, 0, 0);
            accB[n2] = __builtin_amdgcn_mfma_f32_16x16x32_f16(vt, bl, accB[n2], 0, 0, 0);
        }

#pragma unroll
        for (int n2 = 0; n2 < 2; n2++) {
            int l = n2 * 16 + l15;
            if (l < LC) {
#pragma unroll
                for (int r = 0; r < 4; r++) {
                    int d = d0 + rq + r;
                    float vv = Vb[(size_t)l * CTXM + d];
                    float a  = accA[n2][r];
                    float bv = accB[n2][r];
                    size_t base = (size_t)d * LC + l;
                    outb[base]                 = vv;
                    outb[base + CTXM * LC]     = a;
                    outb[base + 2 * CTXM * LC] = vv * a;
                    outb[base + 3 * CTXM * LC] = vv * bv;
                }
            }
        }
    }
}

extern "C" void kernel_launch(void* const* d_in, const int* in_sizes, int n_in,
                              void* d_out, int out_size, void* d_ws, size_t ws_size,
                              hipStream_t stream) {
    const float* Vid   = (const float*)d_in[0];
    const float* Ques  = (const float*)d_in[1];
    const float* Vmask = (const float*)d_in[2];
    const float* Qmask = (const float*)d_in[3];
    const float* tv    = (const float*)d_in[4];
    const float* tg    = (const float*)d_in[5];
    const float* tb    = (const float*)d_in[6];
    const float* w4V   = (const float*)d_in[7];
    const float* w4Q   = (const float*)d_in[8];
    const float* w4mlu = (const float*)d_in[9];
    const float* bias  = (const float*)d_in[10];
    float* out = (float*)d_out;

    float* scale = (float*)d_ws;          // 512 floats
    float* V     = scale + 512;           // 40960*512 floats (84 MB)

    scale_kernel<<<512, 256, 0, stream>>>(tv, tg, scale);
    gemm_kernel<<<1280, 256, 0, stream>>>(Vid, tv, scale, tb, V);
    attn_kernel<<<B_, 512, 0, stream>>>(Ques, Vmask, Qmask, w4V, w4Q, w4mlu, bias, V, out);
}

// Round 10
// 531.988 us; speedup vs baseline: 1.3770x; 1.0961x over previous
//
#include <hip/hip_runtime.h>
#include <math.h>

#define B_    2048
#define LC    20
#define LQ    50
#define CTX   2048
#define CTXM  512
#define NEGV  -1e30f

typedef __fp16 half8 __attribute__((ext_vector_type(8)));
typedef __fp16 f16x2 __attribute__((ext_vector_type(2)));
typedef float f32x4  __attribute__((ext_vector_type(4)));
typedef unsigned int uint;

// ---------------- helpers: fp32 -> fp16 conversions ----------------
__device__ __forceinline__ uint2 cvt4_pack(float4 v) {
    union { f16x2 h[2]; uint2 u; } r;
    r.h[0] = __builtin_amdgcn_cvt_pkrtz(v.x, v.y);
    r.h[1] = __builtin_amdgcn_cvt_pkrtz(v.z, v.w);
    return r.u;
}
__device__ __forceinline__ half8 cvt8(const float* x) {
    union { f16x2 h[4]; half8 v; } r;
    r.h[0] = __builtin_amdgcn_cvt_pkrtz(x[0], x[1]);
    r.h[1] = __builtin_amdgcn_cvt_pkrtz(x[2], x[3]);
    r.h[2] = __builtin_amdgcn_cvt_pkrtz(x[4], x[5]);
    r.h[3] = __builtin_amdgcn_cvt_pkrtz(x[6], x[7]);
    return r.v;
}

#define GLOAD_LDS16(g, l)                                                        \
    __builtin_amdgcn_global_load_lds(                                            \
        (const __attribute__((address_space(1))) unsigned int*)(g),              \
        (__attribute__((address_space(3))) unsigned int*)(l), 16, 0, 0)

// ---------------- Kernel 1: per-row scale = g[m] / ||trans_v[m,:]|| ----------------
__global__ __launch_bounds__(256)
void scale_kernel(const float* __restrict__ trans_v,
                  const float* __restrict__ trans_g,
                  float* __restrict__ scale) {
    int m = blockIdx.x;
    int t = threadIdx.x;
    const float* row = trans_v + (size_t)m * CTX;
    float ss = 0.f;
    for (int i = t; i < CTX; i += 256) { float v = row[i]; ss += v * v; }
    __shared__ float red[256];
    red[t] = ss;
    __syncthreads();
    for (int s = 128; s > 0; s >>= 1) {
        if (t < s) red[t] += red[t + s];
        __syncthreads();
    }
    if (t == 0) scale[m] = trans_g[m] / sqrtf(red[0]);
}

// ---------------- Kernel 1b: pack B = scale*Wt as fp16 hi/lo, pre-swizzled tile order ----
// Bp layout: [nslab 2][kchunk 64][r 256][cphys 128B]; value at cphys comes from
// clog = cphys ^ ((r&7)<<4): clog<64 -> hi term, else lo; k = kchunk*32 + (clog&63)/2.
__global__ __launch_bounds__(256)
void bpack_kernel(const float* __restrict__ Wt,
                  const float* __restrict__ scale,
                  char* __restrict__ Bp) {
    int u = blockIdx.x * 256 + threadIdx.x;     // one 16B unit, 262144 total
    size_t o = (size_t)u * 16;
    int nslab  = (int)(o >> 21);
    int rem    = (int)(o & 2097151);
    int kchunk = rem >> 15;
    int rem2   = rem & 32767;
    int r      = rem2 >> 7;
    int cphys  = rem2 & 127;                    // 16B aligned
    int clog   = cphys ^ ((r & 7) << 4);
    int isLo   = clog >> 6;
    int k0     = kchunk * 32 + ((clog & 63) >> 1);
    int n      = nslab * 256 + r;
    float s = scale[n];
    const float* wr = Wt + (size_t)n * CTX + k0;
    union { __fp16 h[8]; uint4 u4; } out;
#pragma unroll
    for (int e = 0; e < 8; e++) {
        float w = wr[e] * s;
        __fp16 hi = (__fp16)w;
        out.h[e] = isLo ? (__fp16)(w - (float)hi) : hi;
    }
    *(uint4*)&Bp[o] = out.u4;
}

// ---------------- Kernel 2: fp16 2-term GEMM, 64x256 tile, gload_lds dbuf ----------------
// C[m][n] = sum_k A[m][k] * (scale*Wt)[n][k]; A single fp16 term, B hi+lo.
__global__ __launch_bounds__(512, 4)
void gemm_kernel(const float* __restrict__ A,        // (40960, 2048) fp32
                 const char*  __restrict__ Bp,       // packed pre-swizzled
                 const float* __restrict__ trans_b,  // (512)
                 float* __restrict__ V)              // (40960, 512)
{
    // LDS: [0,65536): B dbuf 2x32KB (rows 256 x 128B hi|lo, XOR ((r&7)<<4))
    //      [65536,73728): A dbuf 2x4KB (rows 64 x 64B, XOR ((r&3)<<4))
    __shared__ char lds[73728] __attribute__((aligned(16)));

    int t = threadIdx.x;
    int orig = blockIdx.x;
    int wg = (orig & 7) * 160 + (orig >> 3);    // bijective XCD swizzle (1280 % 8 == 0)
    int nslab = wg & 1;
    int m0 = (wg >> 1) * 64;
    int n0 = nslab << 8;

    int wid = t >> 6, lane = t & 63;
    int l15 = lane & 15;
    int q16 = (lane >> 4) << 4;                 // k-slice byte offset (8 fp16)
    int rq  = (lane >> 4) << 2;                 // C row-group offset
    int wm = (wid >> 2) << 5;                   // 0 / 32
    int wn = (wid & 3) << 6;                    // 0 / 64 / 128 / 192

    // staging indices
    int r_a   = t >> 3;                         // A row 0..63
    int kc4   = (t & 7) << 2;                   // fp32 col in 32-chunk
    int a_dst = 65536 + r_a * 64 + (((t & 7) << 3) ^ ((r_a & 3) << 4));
    const char* bslab = Bp + (size_t)nslab * (64 * 32768);
    const float* arow = A + (size_t)(m0 + r_a) * CTX + kc4;

    f32x4 acc[2][4];
#pragma unroll
    for (int i = 0; i < 2; i++)
#pragma unroll
        for (int j = 0; j < 4; j++) acc[i][j] = (f32x4){0.f, 0.f, 0.f, 0.f};

    // prologue: B chunk 0 -> buf0, A chunk 0 -> ra
    {
        const char* src = bslab + t * 16;
#pragma unroll
        for (int i = 0; i < 4; i++)
            GLOAD_LDS16(src + i * 8192, lds + i * 8192 + t * 16);
    }
    float4 ra = *(const float4*)arow;

    int cur = 0;
    for (int it = 0; it < 64; ++it) {
        // A convert + LDS write into buf[cur]
        *(uint2*)&lds[a_dst + cur * 4096] = cvt4_pack(ra);
        __syncthreads();   // drains B[cur] gloads (vmcnt) + A writes (lgkm); separates buffer reuse

        if (it + 1 < 64) {
            const char* src = bslab + (size_t)(it + 1) * 32768 + t * 16;
            char* dst = lds + (cur ^ 1) * 32768 + t * 16;
#pragma unroll
            for (int i = 0; i < 4; i++)
                GLOAD_LDS16(src + i * 8192, dst + i * 8192);
            ra = *(const float4*)(arow + (it + 1) * 32);
        }

        // MFMA phase on buf[cur]
        const char* Ab = lds + 65536 + cur * 4096;
        const char* Bb = lds + cur * 32768;
        half8 af[2];
#pragma unroll
        for (int mt = 0; mt < 2; mt++) {
            int r = wm + mt * 16 + l15;
            af[mt] = *(const half8*)&Ab[r * 64 + (q16 ^ ((r & 3) << 4))];
        }
#pragma unroll
        for (int nt = 0; nt < 4; nt++) {
            int r = wn + nt * 16 + l15;
            half8 bh = *(const half8*)&Bb[r * 128 + (q16 ^ ((r & 7) << 4))];
#pragma unroll
            for (int mt = 0; mt < 2; mt++)
                acc[mt][nt] = __builtin_amdgcn_mfma_f32_16x16x32_f16(af[mt], bh, acc[mt][nt], 0, 0, 0);
        }
#pragma unroll
        for (int nt = 0; nt < 4; nt++) {
            int r = wn + nt * 16 + l15;
            half8 bl = *(const half8*)&Bb[r * 128 + ((64 + q16) ^ ((r & 7) << 4))];
#pragma unroll
            for (int mt = 0; mt < 2; mt++)
                acc[mt][nt] = __builtin_amdgcn_mfma_f32_16x16x32_f16(af[mt], bl, acc[mt][nt], 0, 0, 0);
        }
        cur ^= 1;
    }

    // epilogue: +trans_b, store
#pragma unroll
    for (int nt = 0; nt < 4; nt++) {
        int col = n0 + wn + nt * 16 + l15;
        float tb = trans_b[col];
#pragma unroll
        for (int mt = 0; mt < 2; mt++) {
            int m = m0 + wm + mt * 16 + rq;
#pragma unroll
            for (int rg = 0; rg < 4; rg++)
                V[(size_t)(m + rg) * CTXM + col] = acc[mt][nt][rg] + tb;
        }
    }
}

// ---------------- Kernel 3: MFMA attention (fp16 operands, unchanged from R7) ----------------
__global__ __launch_bounds__(512, 4)
void attn_kernel(const float* __restrict__ Ques,    // (B, 512, 50)
                 const float* __restrict__ V_mask,  // (B, 20)
                 const float* __restrict__ Q_mask,  // (B, 50)
                 const float* __restrict__ w4V,     // (512)
                 const float* __restrict__ w4Q,     // (512)
                 const float* __restrict__ w4mlu,   // (512)
                 const float* __restrict__ bias,    // (1)
                 const float* __restrict__ V,       // (B*20, 512)
                 float* __restrict__ out)           // (B, 2048, 20)
{
    __shared__ float Ssh[LC][LQ];
    __shared__ float S1f[LC][LQ];
    __shared__ float S2f[LC][LQ];
    __shared__ __fp16 S1h[LC][72];
    __shared__ __fp16 S1l[LC][72];
    __shared__ __fp16 Bth[LC][40];
    __shared__ __fp16 Btl[LC][40];
    __shared__ float s1p[8][LQ];
    __shared__ float s0sh[LC];
    __shared__ float s1qsh[LQ];
    __shared__ float qmsh[LQ];
    __shared__ float vmsh[LC];

    int b = blockIdx.x;
    int t = threadIdx.x;
    int wid = t >> 6, lane = t & 63;
    int l15 = lane & 15;
    int kq  = (lane >> 4) << 3;
    int rq  = (lane >> 4) << 2;
    const float* Qb = Ques + (size_t)b * (CTXM * LQ);
    const float* Vb = V + (size_t)b * (LC * CTXM);

    if (t < LQ) qmsh[t] = Q_mask[(size_t)b * LQ + t];
    else if (t >= 64 && t < 64 + LC) vmsh[t - 64] = V_mask[(size_t)b * LC + (t - 64)];

    for (int l = wid; l < LC; l += 8) {
        float a = 0.f;
        const float* vr = Vb + (size_t)l * CTXM;
#pragma unroll
        for (int i = 0; i < CTXM / 64; i++)
            a = fmaf(vr[lane + 64 * i], w4V[lane + 64 * i], a);
#pragma unroll
        for (int o = 32; o > 0; o >>= 1) a += __shfl_xor(a, o);
        if (lane == 0) s0sh[l] = a;
    }

    {
        int q = (lane < LQ) ? lane : (LQ - 1);
        float a = 0.f;
        for (int i = 0; i < 64; i++) {
            int d = (wid << 6) + i;
            a = fmaf(Qb[(size_t)d * LQ + q], w4Q[d], a);
        }
        if (lane < LQ) s1p[wid][lane] = a;
    }

    int mt = wid >> 2, nt = wid & 3;
    f32x4 accS = {0.f, 0.f, 0.f, 0.f};
    {
        int lA = mt * 16 + l15; if (lA > LC - 1) lA = LC - 1;
        int qB = nt * 16 + l15; if (qB > LQ - 1) qB = LQ - 1;
        const float* vrow = Vb + (size_t)lA * CTXM;
        for (int kt = 0; kt < 16; kt++) {
            int d0 = kt * 32 + kq;
            float xa[8], xb[8];
            float4 va = *(const float4*)&vrow[d0];
            float4 vc = *(const float4*)&vrow[d0 + 4];
            float4 wa = *(const float4*)&w4mlu[d0];
            float4 wc = *(const float4*)&w4mlu[d0 + 4];
            xa[0] = va.x * wa.x; xa[1] = va.y * wa.y; xa[2] = va.z * wa.z; xa[3] = va.w * wa.w;
            xa[4] = vc.x * wc.x; xa[5] = vc.y * wc.y; xa[6] = vc.z * wc.z; xa[7] = vc.w * wc.w;
#pragma unroll
            for (int e = 0; e < 8; e++) xb[e] = Qb[(size_t)(d0 + e) * LQ + qB];
            half8 vf = cvt8(xa);
            half8 qf = cvt8(xb);
            accS = __builtin_amdgcn_mfma_f32_16x16x32_f16(vf, qf, accS, 0, 0, 0);
        }
    }
    __syncthreads();   // BAR1

    if (t < LQ) {
        float s = 0.f;
#pragma unroll
        for (int w = 0; w < 8; w++) s += s1p[w][t];
        s1qsh[t] = s;
    }
    __syncthreads();   // BAR2

    {
        float bb = bias[0];
        int q = nt * 16 + l15;
#pragma unroll
        for (int r = 0; r < 4; r++) {
            int l = mt * 16 + rq + r;
            if (l < LC && q < LQ)
                Ssh[l][q] = accS[r] + s0sh[l] + s1qsh[q] + bb;
        }
    }
    __syncthreads();   // BAR3

    for (int l = wid; l < LC; l += 8) {
        float x;
        if (lane < LQ) {
            float qm = qmsh[lane];
            x = Ssh[l][lane] * qm + (1.f - qm) * NEGV;
        } else x = -INFINITY;
        float mx = x;
#pragma unroll
        for (int o = 32; o > 0; o >>= 1) mx = fmaxf(mx, __shfl_xor(mx, o));
        float e = (lane < LQ) ? expf(x - mx) : 0.f;
        float sum = e;
#pragma unroll
        for (int o = 32; o > 0; o >>= 1) sum += __shfl_xor(sum, o);
        float p = e / sum;
        if (lane < LQ) S1f[l][lane] = p;
        __fp16 hs = (__fp16)p;
        __fp16 ls = (__fp16)(p - (float)hs);
        S1h[l][lane] = (lane < LQ) ? hs : (__fp16)0;
        S1l[l][lane] = (lane < LQ) ? ls : (__fp16)0;
    }

    for (int ci = 0; ci < 7; ci++) {
        int c = wid * 7 + ci;
        if (c < LQ) {
            float x;
            if (lane < LC) {
                float vm = vmsh[lane];
                x = Ssh[lane][c] * vm + (1.f - vm) * NEGV;
            } else x = -INFINITY;
            float mx = x;
#pragma unroll
            for (int o = 32; o > 0; o >>= 1) mx = fmaxf(mx, __shfl_xor(mx, o));
            float e = (lane < LC) ? expf(x - mx) : 0.f;
            float sum = e;
#pragma unroll
            for (int o = 32; o > 0; o >>= 1) sum += __shfl_xor(sum, o);
            if (lane < LC) S2f[lane][c] = e / sum;
        }
    }
    __syncthreads();   // BAR4

    if (t < LC * LC) {
        int l = t % LC, m = t / LC;
        float s = 0.f;
#pragma unroll
        for (int j = 0; j < LQ; j++) s = fmaf(S1f[l][j], S2f[m][j], s);
        __fp16 hs = (__fp16)s;
        Bth[l][m] = hs;
        Btl[l][m] = (__fp16)(s - (float)hs);
    }
    if (t < 240) {
        int l = t % LC, m = LC + t / LC;
        Bth[l][m] = (__fp16)0; Btl[l][m] = (__fp16)0;
    }
    __syncthreads();   // BAR5

    float* outb = out + (size_t)b * (4 * CTXM * LC);
#pragma unroll 1
    for (int i = 0; i < 4; i++) {
        int dt = wid + 8 * i;
        int d0 = dt * 16;
        int dq = d0 + l15;
        const float* qrow = Qb + (size_t)dq * LQ;
        float xa[8];
#pragma unroll
        for (int e = 0; e < 8; e++) xa[e] = qrow[kq + e];
        half8 qf0 = cvt8(xa);
#pragma unroll
        for (int e = 0; e < 8; e++) {
            int j = 32 + kq + e;
            xa[e] = (j < LQ) ? qrow[j] : 0.f;
        }
        half8 qf1 = cvt8(xa);
        float xv[8];
#pragma unroll
        for (int e = 0; e < 8; e++) {
            int m = kq + e;
            int mc = (m < LC) ? m : 0;
            float vv = Vb[(size_t)mc * CTXM + d0 + l15];
            xv[e] = (m < LC) ? vv : 0.f;
        }
        half8 vt = cvt8(xv);

        f32x4 accA[2] = {{0.f,0.f,0.f,0.f},{0.f,0.f,0.f,0.f}};
        f32x4 accB[2] = {{0.f,0.f,0.f,0.f},{0.f,0.f,0.f,0.f}};
#pragma unroll
        for (int n2 = 0; n2 < 2; n2++) {
            int lS = n2 * 16 + l15; if (lS > LC - 1) lS = LC - 1;
            half8 s1h0 = *(const half8*)&S1h[lS][kq];
            half8 s1l0 = *(const half8*)&S1l[lS][kq];
            half8 s1h1 = *(const half8*)&S1h[lS][32 + kq];
            half8 s1l1 = *(const half8*)&S1l[lS][32 + kq];
            accA[n2] = __builtin_amdgcn_mfma_f32_16x16x32_f16(qf0, s1h0, accA[n2], 0, 0, 0);
            accA[n2] = __builtin_amdgcn_mfma_f32_16x16x32_f16(qf0, s1l0, accA[n2], 0, 0, 0);
            accA[n2] = __builtin_amdgcn_mfma_f32_16x16x32_f16(qf1, s1h1, accA[n2], 0, 0, 0);
            accA[n2] = __builtin_amdgcn_mfma_f32_16x16x32_f16(qf1, s1l1, accA[n2], 0, 0, 0);
            half8 bh = *(const half8*)&Bth[lS][kq];
            half8 bl = *(const half8*)&Btl[lS][kq];
            accB[n2] = __builtin_amdgcn_mfma_f32_16x16x32_f16(vt, bh, accB[n2], 0, 0, 0);
            accB[n2] = __builtin_amdgcn_mfma_f32_16x16x32_f16(vt, bl, accB[n2], 0, 0, 0);
        }

#pragma unroll
        for (int n2 = 0; n2 < 2; n2++) {
            int l = n2 * 16 + l15;
            if (l < LC) {
#pragma unroll
                for (int r = 0; r < 4; r++) {
                    int d = d0 + rq + r;
                    float vv = Vb[(size_t)l * CTXM + d];
                    float a  = accA[n2][r];
                    float bv = accB[n2][r];
                    size_t base = (size_t)d * LC + l;
                    outb[base]                 = vv;
                    outb[base + CTXM * LC]     = a;
                    outb[base + 2 * CTXM * LC] = vv * a;
                    outb[base + 3 * CTXM * LC] = vv * bv;
                }
            }
        }
    }
}

extern "C" void kernel_launch(void* const* d_in, const int* in_sizes, int n_in,
                              void* d_out, int out_size, void* d_ws, size_t ws_size,
                              hipStream_t stream) {
    const float* Vid   = (const float*)d_in[0];
    const float* Ques  = (const float*)d_in[1];
    const float* Vmask = (const float*)d_in[2];
    const float* Qmask = (const float*)d_in[3];
    const float* tv    = (const float*)d_in[4];
    const float* tg    = (const float*)d_in[5];
    const float* tb    = (const float*)d_in[6];
    const float* w4V   = (const float*)d_in[7];
    const float* w4Q   = (const float*)d_in[8];
    const float* w4mlu = (const float*)d_in[9];
    const float* bias  = (const float*)d_in[10];
    float* out = (float*)d_out;

    float* scale = (float*)d_ws;                         // 512 f
    float* V     = scale + 512;                          // 40960*512 f (84 MB)
    char*  Bp    = (char*)(V + (size_t)40960 * 512);     // 4 MB packed B

    scale_kernel<<<512, 256, 0, stream>>>(tv, tg, scale);
    bpack_kernel<<<1024, 256, 0, stream>>>(tv, scale, Bp);
    gemm_kernel<<<1280, 512, 0, stream>>>(Vid, Bp, tb, V);
    attn_kernel<<<B_, 512, 0, stream>>>(Ques, Vmask, Qmask, w4V, w4Q, w4mlu, bias, V, out);
}